// Round 7
// baseline (505.500 us; speedup 1.0000x reference)
//
#include <hip/hip_runtime.h>
#include <math.h>

#define HID 50
#define TT  512
#define BT  8       // batch per block
#define NW  4       // waves per block
#define HS  72      // H plane row stride in shorts
#define XS  513     // x_lds row stride (floats)
#define YS  (BT+1)  // y_lds row stride (floats)

typedef __attribute__((ext_vector_type(8))) short bf16x8;
typedef __attribute__((ext_vector_type(4))) float f32x4;

__device__ __forceinline__ float sigmoid_fast(float x) {
    return __builtin_amdgcn_rcpf(1.f + __builtin_amdgcn_exp2f(-1.44269504088896f * x));
}
__device__ __forceinline__ float tanh_fast(float x) {
    return fmaf(2.f, __builtin_amdgcn_rcpf(1.f + __builtin_amdgcn_exp2f(-2.88539008177793f * x)), -1.f);
}
__device__ __forceinline__ short bf16_rtne(float f) {
    unsigned u = __float_as_uint(f);
    u = (u + 0x7FFFu + ((u >> 16) & 1u)) >> 16;
    return (short)u;
}
__device__ __forceinline__ float bf16_f32(short s) {
    return __uint_as_float(((unsigned)(unsigned short)s) << 16);
}

// Block = 256 threads (4 waves), BT=8 batch; grid = 512 blocks = 2 blocks/CU.
// The two co-resident blocks have INDEPENDENT barriers, so their phase bursts
// (LDS read -> MFMA -> trans -> write) interleave and fill each other's idle
// pipes -- attacking R5's burst-serialization (1514 cyc/step vs ~900 pipe sum).
// 13 real M-tiles (208 rows) pruned from 16: waves get {3,3,3,4} tiles; the
// all-phantom row-iterations of R5's wv6/wv7 are gone. No global memory ops
// in the loop: y accumulates in y_lds, bulk-stored at the end.
// MFMA cols 8..15 are phantom batch (B read col&7 -> duplicate, discarded).
// K-slots: 0..49 = W_hh cols, 50 = x_hi, 51 = bias (B=1.0), 52 = x_lo, 53..63 = 0.
__global__ __launch_bounds__(256) void lstm_mfma4_kernel(
    const float* __restrict__ x,      // [B, T]
    const float* __restrict__ W_ih,   // [200, 1]
    const float* __restrict__ W_hh,   // [200, 50]
    const float* __restrict__ b_ih,   // [200]
    const float* __restrict__ b_hh,   // [200]
    const float* __restrict__ W_out,  // [1, 50]
    const float* __restrict__ b_out,  // [1]
    float* __restrict__ out)          // [B, T]
{
    const int tid  = threadIdx.x;
    const int lane = tid & 63;
    const int wv   = tid >> 6;       // 0..3
    const int col  = lane & 15;      // B/D col (batch; >=8 phantom)
    const int quad = lane >> 4;      // k-octet / D row-group

    __shared__ __align__(16) unsigned short Hh[2][BT][HS];
    __shared__ float x_lds[BT][XS];
    __shared__ float y_lds[TT][YS];
    __shared__ float ypart[2][NW][16];

    // zero both H buffers (k-slots 53..63 + pads must stay 0)
    for (int i = tid; i < 2 * BT * HS; i += 256)
        (&Hh[0][0][0])[i] = 0;
    // stage x[block,:,:] -> LDS (coalesced float4 reads)
    {
        const float4* xg = (const float4*)(x + (size_t)blockIdx.x * BT * TT);
        #pragma unroll
        for (int pk = 0; pk < (BT * TT / 4) / 256; ++pk) {   // 4 iters
            const int idx = pk * 256 + tid;                  // float4 index
            const float4 v = xg[idx];
            const int fb = (idx * 4) >> 9;
            const int ft = (idx * 4) & 511;
            x_lds[fb][ft + 0] = v.x; x_lds[fb][ft + 1] = v.y;
            x_lds[fb][ft + 2] = v.z; x_lds[fb][ft + 3] = v.w;
        }
    }

    // tile assignment: wave wv owns tiles [base, base+cnt), {3,3,3,4}
    const int base = wv * 3;
    const int cnt  = 3 + (wv == 3 ? 1 : 0);

    // persistent A fragments (hi/lo split bf16)
    bf16x8 Ahi[4][2], Alo[4][2];
    #pragma unroll
    for (int i = 0; i < 4; ++i) {
        #pragma unroll
        for (int kk = 0; kk < 2; ++kk) {
            #pragma unroll
            for (int j = 0; j < 8; ++j) { Ahi[i][kk][j] = 0; Alo[i][kk][j] = 0; }
        }
        if (i < cnt) {
            const int gh  = (base + i) * 16 + col;   // g^ row
            const int u   = gh >> 2;
            const int ty  = gh & 3;
            const bool vl = (u < HID);
            const int og  = ty * HID + u;            // original gate row
            #pragma unroll
            for (int kk = 0; kk < 2; ++kk) {
                #pragma unroll
                for (int j = 0; j < 8; ++j) {
                    const int k = kk * 32 + quad * 8 + j;
                    float v = 0.f;
                    if (vl) {
                        if (k < HID)       v = W_hh[og * HID + k];
                        else if (k == 50)  v = W_ih[og];       // x_hi slot
                        else if (k == 51)  v = b_ih[og] + b_hh[og];
                        else if (k == 52)  v = W_ih[og];       // x_lo slot
                    }
                    const short hi = bf16_rtne(v);
                    Ahi[i][kk][j] = hi;
                    Alo[i][kk][j] = bf16_rtne(v - bf16_f32(hi));
                }
            }
        }
    }

    // act-phase state: lane owns unit u_i = (base+i)*4 + quad for batch col
    float c[4] = {0.f, 0.f, 0.f, 0.f};
    float wo[4];
    #pragma unroll
    for (int i = 0; i < 4; ++i) {
        const int u = (base + i) * 4 + quad;
        wo[i] = (i < cnt && u < HID) ? W_out[u] : 0.f;
    }
    const float bo = b_out[0];

    __syncthreads();    // x_lds + zeroed H visible

    if (tid < BT) {     // bias slot (both buffers), x_0 hi/lo (buffer 0)
        Hh[0][tid][51] = 0x3F80;
        Hh[1][tid][51] = 0x3F80;
        const float x0 = x_lds[tid][0];
        const short h0 = bf16_rtne(x0);
        Hh[0][tid][50] = (unsigned short)h0;
        Hh[0][tid][52] = (unsigned short)bf16_rtne(x0 - bf16_f32(h0));
    }
    __syncthreads();

    for (int t = 0; t < TT; ++t) {
        const int p = t & 1;        // read buffer; write 1-p

        // y_{t-1} -> y_lds (LDS only; no global ops in the loop)
        if (t > 0 && tid < BT) {
            float s = bo;
            #pragma unroll
            for (int w = 0; w < NW; ++w) s += ypart[1 - p][w][tid];
            y_lds[t - 1][tid] = s;
        }

        // B fragments: B[k=kk*32+quad*8+j][n=col&7] (cols 8..15 duplicate)
        bf16x8 Bh[2];
        #pragma unroll
        for (int kk = 0; kk < 2; ++kk)
            Bh[kk] = *(const bf16x8*)&Hh[p][col & 7][kk * 32 + quad * 8];

        float psum = 0.f;
        #pragma unroll
        for (int i = 0; i < 4; ++i) {
            if (i < cnt) {
                f32x4 acc = {0.f, 0.f, 0.f, 0.f};
                #pragma unroll
                for (int kk = 0; kk < 2; ++kk) {
                    acc = __builtin_amdgcn_mfma_f32_16x16x32_bf16(Ahi[i][kk], Bh[kk], acc, 0, 0, 0);
                    acc = __builtin_amdgcn_mfma_f32_16x16x32_bf16(Alo[i][kk], Bh[kk], acc, 0, 0, 0);
                }
                // acc = {pre_i, pre_f, pre_g, pre_o} of unit u, batch col
                const int u = (base + i) * 4 + quad;
                const float gi = sigmoid_fast(acc.x);
                const float gf = sigmoid_fast(acc.y);
                const float gg = tanh_fast(acc.z);
                const float go = sigmoid_fast(acc.w);
                c[i] = fmaf(gf, c[i], gi * gg);
                const float h = go * tanh_fast(c[i]);
                if (u < HID && col < BT)   // real unit, real batch col
                    Hh[1 - p][col][u] = (unsigned short)bf16_rtne(h);
                psum = fmaf(h, wo[i], psum);
            }
        }

        // x_{t+1} hi/lo into the write buffer
        if (tid < BT) {
            const float xn = x_lds[tid][(t + 1 < TT) ? t + 1 : t];
            const short hx = bf16_rtne(xn);
            Hh[1 - p][tid][50] = (unsigned short)hx;
            Hh[1 - p][tid][52] = (unsigned short)bf16_rtne(xn - bf16_f32(hx));
        }

        // per-wave y partial: sum over quad groups
        psum += __shfl_xor(psum, 16);
        psum += __shfl_xor(psum, 32);
        if (lane < BT) ypart[p][wv][lane] = psum;

        __syncthreads();    // the ONE barrier (LDS-only drain)
    }

    // epilogue: y_{TT-1}, then bulk coalesced store
    if (tid < BT) {
        float s = bo;
        #pragma unroll
        for (int w = 0; w < NW; ++w) s += ypart[(TT - 1) & 1][w][tid];
        y_lds[TT - 1][tid] = s;
    }
    __syncthreads();
    {
        float* yout = out + (size_t)blockIdx.x * BT * TT;
        #pragma unroll
        for (int pk = 0; pk < BT * TT / 256; ++pk) {   // 16 iters
            const int idx = pk * 256 + tid;
            const int bb  = idx >> 9;                  // batch row
            const int t   = idx & 511;
            yout[idx] = y_lds[t][bb];                  // conflict-free (YS=9 odd)
        }
    }
}

extern "C" void kernel_launch(void* const* d_in, const int* in_sizes, int n_in,
                              void* d_out, int out_size, void* d_ws, size_t ws_size,
                              hipStream_t stream) {
    const float* x     = (const float*)d_in[0];
    const float* W_ih  = (const float*)d_in[1];
    const float* W_hh  = (const float*)d_in[2];
    const float* b_ih  = (const float*)d_in[3];
    const float* b_hh  = (const float*)d_in[4];
    const float* W_out = (const float*)d_in[5];
    const float* b_out = (const float*)d_in[6];
    float* out = (float*)d_out;

    const int B = in_sizes[0] / TT;          // 4096
    lstm_mfma4_kernel<<<B / BT, 256, 0, stream>>>(x, W_ih, W_hh, b_ih, b_hh,
                                                  W_out, b_out, out);
}

// Round 8
// 366.375 us; speedup vs baseline: 1.3797x; 1.3797x over previous
//
#include <hip/hip_runtime.h>
#include <math.h>

#define HID 50
#define TT  512
#define BT  16      // batch per block (= MFMA N, all cols real)
#define NT  13      // M-tiles (208 gate rows >= 200 real)
#define HS  72      // H plane row stride in shorts
#define XS  513     // x_lds row stride (floats): +1 bank/row -> conflict-free column read

typedef __attribute__((ext_vector_type(8))) short bf16x8;
typedef __attribute__((ext_vector_type(4))) float f32x4;

__device__ __forceinline__ float sigmoid_fast(float x) {
    return __builtin_amdgcn_rcpf(1.f + __builtin_amdgcn_exp2f(-1.44269504088896f * x));
}
__device__ __forceinline__ float tanh_fast(float x) {
    return fmaf(2.f, __builtin_amdgcn_rcpf(1.f + __builtin_amdgcn_exp2f(-2.88539008177793f * x)), -1.f);
}
__device__ __forceinline__ short bf16_rtne(float f) {
    unsigned u = __float_as_uint(f);
    u = (u + 0x7FFFu + ((u >> 16) & 1u)) >> 16;
    return (short)u;
}
__device__ __forceinline__ float bf16_f32(short s) {
    return __uint_as_float(((unsigned)(unsigned short)s) << 16);
}

// Block = 1024 threads (16 waves), BT=16 batch, grid 256 = 1 block/CU.
// Waves 0..12: ONE M-tile each (16 g^ rows = 4 units x 4 gate types).
//   -> 4 waves/SIMD of TLP, short per-wave critical path, 832/800 pairs (96% real).
// Wave 13: y chore -- reduces ypart[t-1] and global-stores it (only wave with
//   vmcnt at the barrier; issued early, retires under compute).
// Wave 14: x chore -- stages x_{t+1} hi/lo into the write H buffer.
// Wave 15: idle (barrier only).
// Numerics identical to R5: A split hi+lo bf16, H single bf16, x hi/lo K-slots.
// K-slots: 0..49 = W_hh cols, 50 = x_hi, 51 = bias (B=1.0), 52 = x_lo, 53..63 = 0.
__global__ __launch_bounds__(1024) void lstm_mfma5_kernel(
    const float* __restrict__ x,      // [B, T]
    const float* __restrict__ W_ih,   // [200, 1]
    const float* __restrict__ W_hh,   // [200, 50]
    const float* __restrict__ b_ih,   // [200]
    const float* __restrict__ b_hh,   // [200]
    const float* __restrict__ W_out,  // [1, 50]
    const float* __restrict__ b_out,  // [1]
    float* __restrict__ out)          // [B, T]
{
    const int tid  = threadIdx.x;
    const int lane = tid & 63;
    const int wv   = tid >> 6;       // 0..15
    const int col  = lane & 15;      // A-m / B-n(batch) / D-col(batch)
    const int quad = lane >> 4;      // k-octet / D row-group

    __shared__ __align__(16) unsigned short Hh[2][BT][HS];
    __shared__ float x_lds[BT][XS];
    __shared__ float ypart[2][NT][16];

    // zero both H buffers (k-slots 53..63 + pads must stay 0)
    for (int i = tid; i < 2 * BT * HS; i += 1024)
        (&Hh[0][0][0])[i] = 0;
    // stage x[block,:,:] -> LDS (coalesced float4 reads)
    {
        const float4* xg = (const float4*)(x + (size_t)blockIdx.x * BT * TT);
        #pragma unroll
        for (int pk = 0; pk < (BT * TT / 4) / 1024; ++pk) {  // 2 iters
            const int idx = pk * 1024 + tid;                 // float4 index
            const float4 v = xg[idx];
            const int fb = (idx * 4) >> 9;
            const int ft = (idx * 4) & 511;
            x_lds[fb][ft + 0] = v.x; x_lds[fb][ft + 1] = v.y;
            x_lds[fb][ft + 2] = v.z; x_lds[fb][ft + 3] = v.w;
        }
    }

    // persistent A fragments (hi/lo split bf16) -- compute waves only
    bf16x8 Ahi[2], Alo[2];
    #pragma unroll
    for (int kk = 0; kk < 2; ++kk)
        #pragma unroll
        for (int j = 0; j < 8; ++j) { Ahi[kk][j] = 0; Alo[kk][j] = 0; }
    float c = 0.f, wo = 0.f;
    if (wv < NT) {
        const int gh  = wv * 16 + col;    // g^ row
        const int u   = gh >> 2;
        const int ty  = gh & 3;
        const bool vl = (u < HID);
        const int og  = ty * HID + u;     // original gate row
        #pragma unroll
        for (int kk = 0; kk < 2; ++kk) {
            #pragma unroll
            for (int j = 0; j < 8; ++j) {
                const int k = kk * 32 + quad * 8 + j;
                float v = 0.f;
                if (vl) {
                    if (k < HID)       v = W_hh[og * HID + k];
                    else if (k == 50)  v = W_ih[og];       // x_hi slot
                    else if (k == 51)  v = b_ih[og] + b_hh[og];
                    else if (k == 52)  v = W_ih[og];       // x_lo slot
                }
                const short hi = bf16_rtne(v);
                Ahi[kk][j] = hi;
                Alo[kk][j] = bf16_rtne(v - bf16_f32(hi));
            }
        }
        const int uu = wv * 4 + quad;     // unit owned in act phase (50,51 phantom)
        wo = (uu < HID) ? W_out[uu] : 0.f;
    }
    const float bo = b_out[0];
    float* yout = out + (size_t)blockIdx.x * BT * TT;

    __syncthreads();    // x_lds + zeroed H visible

    if (tid < BT) {     // bias slot (both buffers), x_0 hi/lo (buffer 0)
        Hh[0][tid][51] = 0x3F80;
        Hh[1][tid][51] = 0x3F80;
        const float x0 = x_lds[tid][0];
        const short h0 = bf16_rtne(x0);
        Hh[0][tid][50] = (unsigned short)h0;
        Hh[0][tid][52] = (unsigned short)bf16_rtne(x0 - bf16_f32(h0));
    }
    __syncthreads();

    for (int t = 0; t < TT; ++t) {
        const int p = t & 1;        // read buffer; write 1-p

        if (wv < NT) {
            // ---- compute wave: B frags, MFMA, activation, h write, y partial
            bf16x8 Bh[2];
            #pragma unroll
            for (int kk = 0; kk < 2; ++kk)
                Bh[kk] = *(const bf16x8*)&Hh[p][col][kk * 32 + quad * 8];

            // two independent 2-MFMA chains (hi, lo), then combine
            f32x4 ah = {0.f, 0.f, 0.f, 0.f}, al = {0.f, 0.f, 0.f, 0.f};
            #pragma unroll
            for (int kk = 0; kk < 2; ++kk) {
                ah = __builtin_amdgcn_mfma_f32_16x16x32_bf16(Ahi[kk], Bh[kk], ah, 0, 0, 0);
                al = __builtin_amdgcn_mfma_f32_16x16x32_bf16(Alo[kk], Bh[kk], al, 0, 0, 0);
            }
            const float pre_i = ah.x + al.x;
            const float pre_f = ah.y + al.y;
            const float pre_g = ah.z + al.z;
            const float pre_o = ah.w + al.w;

            const int u = wv * 4 + quad;
            const float gi = sigmoid_fast(pre_i);
            const float gf = sigmoid_fast(pre_f);
            const float gg = tanh_fast(pre_g);
            const float go = sigmoid_fast(pre_o);
            c = fmaf(gf, c, gi * gg);
            const float h = go * tanh_fast(c);
            if (u < HID)
                Hh[1 - p][col][u] = (unsigned short)bf16_rtne(h);

            float psum = h * wo;                 // phantom wo = 0
            psum += __shfl_xor(psum, 16);
            psum += __shfl_xor(psum, 32);
            if (lane < 16) ypart[p][wv][col] = psum;
        } else if (wv == 13) {
            // ---- y chore: reduce + store y_{t-1} (early in step; vmcnt
            // retires under the compute waves' work)
            if (t > 0 && lane < 16) {
                float s = bo;
                #pragma unroll
                for (int i = 0; i < NT; ++i) s += ypart[1 - p][i][lane];
                yout[(size_t)lane * TT + (t - 1)] = s;
            }
        } else if (wv == 14) {
            // ---- x chore: stage x_{t+1} hi/lo into the write buffer
            if (lane < BT) {
                const float xn = x_lds[lane][(t + 1 < TT) ? t + 1 : t];
                const short hx = bf16_rtne(xn);
                Hh[1 - p][lane][50] = (unsigned short)hx;
                Hh[1 - p][lane][52] = (unsigned short)bf16_rtne(xn - bf16_f32(hx));
            }
        }

        __syncthreads();    // the ONE barrier
    }

    // epilogue: y_{TT-1} (ypart[(TT-1)&1] visible after the loop's last barrier)
    if (wv == 13 && lane < 16) {
        float s = bo;
        #pragma unroll
        for (int i = 0; i < NT; ++i) s += ypart[(TT - 1) & 1][i][lane];
        yout[(size_t)lane * TT + (TT - 1)] = s;
    }
}

extern "C" void kernel_launch(void* const* d_in, const int* in_sizes, int n_in,
                              void* d_out, int out_size, void* d_ws, size_t ws_size,
                              hipStream_t stream) {
    const float* x     = (const float*)d_in[0];
    const float* W_ih  = (const float*)d_in[1];
    const float* W_hh  = (const float*)d_in[2];
    const float* b_ih  = (const float*)d_in[3];
    const float* b_hh  = (const float*)d_in[4];
    const float* W_out = (const float*)d_in[5];
    const float* b_out = (const float*)d_in[6];
    float* out = (float*)d_out;

    const int B = in_sizes[0] / TT;          // 4096
    lstm_mfma5_kernel<<<B / BT, 1024, 0, stream>>>(x, W_ih, W_hh, b_ih, b_hh,
                                                   W_out, b_out, out);
}

// Round 9
// 354.561 us; speedup vs baseline: 1.4257x; 1.0333x over previous
//
#include <hip/hip_runtime.h>
#include <math.h>

#define HID 50
#define TT  512
#define BT  16      // batch per block (= MFMA N)
#define NCW 7       // compute waves (13 real M-tiles: 2,2,2,2,2,2,1)
#define HS  72      // H plane row stride in shorts (144B rows, 16B aligned, 2-way banks = free)

typedef __attribute__((ext_vector_type(8))) short bf16x8;
typedef __attribute__((ext_vector_type(4))) float f32x4;

__device__ __forceinline__ float sigmoid_fast(float x) {
    return __builtin_amdgcn_rcpf(1.f + __builtin_amdgcn_exp2f(-1.44269504088896f * x));
}
__device__ __forceinline__ float tanh_fast(float x) {
    return fmaf(2.f, __builtin_amdgcn_rcpf(1.f + __builtin_amdgcn_exp2f(-2.88539008177793f * x)), -1.f);
}
__device__ __forceinline__ unsigned short bf16_rtne(float f) {
    unsigned u = __float_as_uint(f);
    u = (u + 0x7FFFu + ((u >> 16) & 1u)) >> 16;
    return (unsigned short)u;
}
__device__ __forceinline__ float bf16_f32(unsigned short s) {
    return __uint_as_float(((unsigned)s) << 16);
}

// Block = 512 threads (8 waves), BT=16 batch, grid 256 = 1 block/CU, 1 barrier/step.
// G[208 x 16] = A[208 x 64] * H[64 x 16] via mfma_f32_16x16x32_bf16, A SINGLE
// plane (W_hh bf16-only -- the R8 gamble); bias and W_ih*x keep split precision
// through spare K-slots of the same A plane:
//   k 0..49 = W_hh_hi cols | 50 = (Wih_hi, x_hi) | 51 = (bias_hi, 1.0)
//   52 = (Wih_hi, x_lo)    | 53 = (bias_lo, 1.0) | 54 = (Wih_lo, x_hi) | 55..63 = 0
// Waves 0..5: tiles {2w,2w+1}; wave 6: tile 12; wave 7: chore (x prefetch from
// global w/ 1-step reg pipeline, y reduce+store; vmcnt retires under compute).
// Row permutation g^ = u*4+ty: D-frag lane (col,quad) = 4 gate preacts of unit
// u = tile*4+quad, batch col -- activations run on acc regs, h back via b16.
__global__ __launch_bounds__(512, 2) void lstm_mfma6_kernel(
    const float* __restrict__ x,      // [B, T]
    const float* __restrict__ W_ih,   // [200, 1]
    const float* __restrict__ W_hh,   // [200, 50]
    const float* __restrict__ b_ih,   // [200]
    const float* __restrict__ b_hh,   // [200]
    const float* __restrict__ W_out,  // [1, 50]
    const float* __restrict__ b_out,  // [1]
    float* __restrict__ out)          // [B, T]
{
    const int tid  = threadIdx.x;
    const int lane = tid & 63;
    const int wv   = tid >> 6;       // 0..7
    const int col  = lane & 15;      // A-m / B-n(batch) / D-col(batch)
    const int quad = lane >> 4;      // k-octet / D row-group

    __shared__ __align__(16) unsigned short Hh[2][BT][HS];
    __shared__ float ypart[2][NCW][17];

    // zero both H buffers (k-slots 55..63 + phantom h 50/51 + pads stay 0)
    for (int i = tid; i < 2 * BT * HS; i += 512)
        (&Hh[0][0][0])[i] = 0;

    const int  base = wv * 2;                   // first tile of this wave
    const int  cnt  = (wv == 6) ? 1 : 2;        // tiles owned (wv<7)

    // persistent A fragments (single plane)
    bf16x8 Ah[2][2];                            // [tile_i][kk]
    float c[2] = {0.f, 0.f};
    float wo[2] = {0.f, 0.f};
    if (wv < NCW) {
        #pragma unroll
        for (int i = 0; i < 2; ++i) {
            #pragma unroll
            for (int kk = 0; kk < 2; ++kk)
                #pragma unroll
                for (int j = 0; j < 8; ++j) Ah[i][kk][j] = 0;
            if (i < cnt) {
                const int gh  = (base + i) * 16 + col;   // g^ row
                const int u   = gh >> 2;
                const int ty  = gh & 3;
                const bool vl = (u < HID);
                const int og  = ty * HID + u;            // original gate row
                #pragma unroll
                for (int kk = 0; kk < 2; ++kk) {
                    #pragma unroll
                    for (int j = 0; j < 8; ++j) {
                        const int k = kk * 32 + quad * 8 + j;
                        float v = 0.f;
                        if (vl) {
                            if (k < HID)      v = W_hh[og * HID + k];
                            else if (k == 50) v = W_ih[og];
                            else if (k == 51) v = b_ih[og] + b_hh[og];
                            else if (k == 52) v = W_ih[og];
                            else if (k == 53) {
                                const float bb = b_ih[og] + b_hh[og];
                                v = bb - bf16_f32(bf16_rtne(bb));
                            } else if (k == 54) {
                                const float wi = W_ih[og];
                                v = wi - bf16_f32(bf16_rtne(wi));
                            }
                        }
                        Ah[i][kk][j] = (short)bf16_rtne(v);
                    }
                }
                const int uu = (base + i) * 4 + quad;
                wo[i] = (uu < HID) ? W_out[uu] : 0.f;
            }
        }
    }
    const float bo = b_out[0];
    float* yout = out + (size_t)blockIdx.x * BT * TT;

    // chore-wave x pipeline state (lanes 16..31 own batch b = lane-16)
    const float* xrow = x + (size_t)(blockIdx.x * BT + (lane - 16)) * TT;
    float xa = 0.f;
    if (wv == NCW && lane >= 16 && lane < 32)
        xa = xrow[1];                            // x[b][1] for step t=0's write

    __syncthreads();    // zeroed H visible

    // buffer-0 slots for t=0: x_0 hi/lo + bias-1.0 markers (packed b32 writes)
    if (tid < BT) {
        const float x0 = x[(size_t)(blockIdx.x * BT + tid) * TT];
        const unsigned short hx = bf16_rtne(x0);
        const unsigned short lx = bf16_rtne(x0 - bf16_f32(hx));
        unsigned* row32 = (unsigned*)&Hh[0][tid][0];
        row32[25] = (unsigned)hx | (0x3F80u << 16);   // k=50,51
        row32[26] = (unsigned)lx | (0x3F80u << 16);   // k=52,53
        Hh[0][tid][54] = hx;                          // k=54
    }
    __syncthreads();

    for (int t = 0; t < TT; ++t) {
        const int p = t & 1;        // read buffer; write 1-p

        if (wv < NCW) {
            // ---- compute wave ----
            const unsigned short* hrow = &Hh[p][col][0];
            bf16x8 B0 = *(const bf16x8*)&hrow[quad * 8];
            bf16x8 B1 = *(const bf16x8*)&hrow[32 + quad * 8];

            float psum = 0.f;
            #pragma unroll
            for (int i = 0; i < 2; ++i) {
                if (i < cnt) {
                    f32x4 acc = {0.f, 0.f, 0.f, 0.f};
                    acc = __builtin_amdgcn_mfma_f32_16x16x32_bf16(Ah[i][0], B0, acc, 0, 0, 0);
                    acc = __builtin_amdgcn_mfma_f32_16x16x32_bf16(Ah[i][1], B1, acc, 0, 0, 0);
                    // acc = {pre_i, pre_f, pre_g, pre_o} of unit u, batch col
                    const int u = (base + i) * 4 + quad;
                    const float gi = sigmoid_fast(acc.x);
                    const float gf = sigmoid_fast(acc.y);
                    const float gg = tanh_fast(acc.z);
                    const float go = sigmoid_fast(acc.w);
                    c[i] = fmaf(gf, c[i], gi * gg);
                    const float h = go * tanh_fast(c[i]);
                    if (u < HID)
                        Hh[1 - p][col][u] = bf16_rtne(h);
                    psum = fmaf(h, wo[i], psum);
                }
            }
            // per-wave y partial: sum over quad groups
            psum += __shfl_xor(psum, 16);
            psum += __shfl_xor(psum, 32);
            if (lane < 16) ypart[p][wv][lane] = psum;
        } else {
            // ---- chore wave ----
            if (lane < 16) {
                // y_{t-1}: reduce + store (early; retires under compute)
                if (t > 0) {
                    float s = bo;
                    #pragma unroll
                    for (int w = 0; w < NCW; ++w) s += ypart[1 - p][w][lane];
                    yout[(size_t)lane * TT + (t - 1)] = s;
                }
            } else if (lane < 32) {
                // x_{t+1} slots into write buffer from register xa, then
                // prefetch x[b][t+2] (global, L1-resident after first pass)
                const int b = lane - 16;
                const unsigned short hx = bf16_rtne(xa);
                const unsigned short lx = bf16_rtne(xa - bf16_f32(hx));
                unsigned* row32 = (unsigned*)&Hh[1 - p][b][0];
                row32[25] = (unsigned)hx | (0x3F80u << 16);   // k=50,51
                row32[26] = (unsigned)lx | (0x3F80u << 16);   // k=52,53
                Hh[1 - p][b][54] = hx;                        // k=54
                const int nidx = (t + 2 < TT) ? t + 2 : TT - 1;
                xa = xrow[nidx];
            }
        }

        __syncthreads();    // the ONE barrier
    }

    // epilogue: y_{TT-1}
    if (wv == NCW && lane < 16) {
        float s = bo;
        #pragma unroll
        for (int w = 0; w < NCW; ++w) s += ypart[(TT - 1) & 1][w][lane];
        yout[(size_t)lane * TT + (TT - 1)] = s;
    }
}

extern "C" void kernel_launch(void* const* d_in, const int* in_sizes, int n_in,
                              void* d_out, int out_size, void* d_ws, size_t ws_size,
                              hipStream_t stream) {
    const float* x     = (const float*)d_in[0];
    const float* W_ih  = (const float*)d_in[1];
    const float* W_hh  = (const float*)d_in[2];
    const float* b_ih  = (const float*)d_in[3];
    const float* b_hh  = (const float*)d_in[4];
    const float* W_out = (const float*)d_in[5];
    const float* b_out = (const float*)d_in[6];
    float* out = (float*)d_out;

    const int B = in_sizes[0] / TT;          // 4096
    lstm_mfma6_kernel<<<B / BT, 512, 0, stream>>>(x, W_ih, W_hh, b_ih, b_hh,
                                                  W_out, b_out, out);
}